// Round 11
// baseline (35.363 us; speedup 1.0000x reference)
//
#include <hip/hip_runtime.h>
#include <hip/hip_bf16.h>
#include <math.h>

// TTMultiheadAttention via MFMA (round 10 = round 4 + polynomial exp):
//   per s:  W_i[e,d] = sum_q brs_i[e,q] * x[q,s,d]      (mfma 32x32x16 bf16)
//           P_i = exp(W_i)   (brs pre-scaled by cA2_i = A_i/sqrt(32); NATURAL log
//                             domain now -- the log2e factor is dropped)
//           OUT_i[b,d] = sum_e CrT[b,e] * P_i[e,d]      (mfma, b row 16 = ones -> l_i)
//           out[b,s,d] = sum_i OUT_i[b,d] / l_i[d]
// Round-10 change (r8 probe: compute ~14us/rep is VALU/trans-throughput-bound;
// r6/r9 proved more waves don't help): replace the 16 v_exp_f32 per (et,i)
// (~16cyc trans each) with a degree-6 Horner polynomial = 6 full-rate FMAs.
// |w| <= ~1.5 (sigma ~0.07), Taylor-6 rel err <= 2e-4 for |w|<=1; softmax's
// ~256-term normalization dilutes tail error -> well under bf16 rounding floor.

#define SS 512
#define DD 256
#define R2 16
#define NI 3

#define BR_UNITS (NI * 8 * 64)              // 1536 x 16B
#define CR_UNITS (16 * 64)                  // 1024 x 16B
#define ALL_UNITS (BR_UNITS + CR_UNITS)     // 2560 x 16B = 40 KB
#define BR_USH (BR_UNITS * 8)               // 12288 ushorts
#define WS_USH (ALL_UNITS * 8)              // 20480 ushorts

typedef __attribute__((ext_vector_type(8))) short bf16x8;
typedef __attribute__((ext_vector_type(8))) unsigned short ushort8;
typedef __attribute__((ext_vector_type(16))) float f32x16;
typedef __attribute__((ext_vector_type(2))) unsigned uint2v;

union B8 { unsigned w[4]; bf16x8 v; };

static __device__ __forceinline__ unsigned short bf16bits(float f) {
    union { __hip_bfloat16 h; unsigned short u; } c;
    c.h = __float2bfloat16(f);
    return c.u;
}
static __device__ __forceinline__ unsigned packb(float a, float b) {
    union { __hip_bfloat162 h; unsigned u; } c;
    c.h = __float22bfloat162_rn(make_float2(a, b));
    return c.u;
}
// e^w via degree-6 Taylor (Horner, 6 FMA, full-rate VALU; no trans pipe).
static __device__ __forceinline__ float exp_poly(float w) {
    float t = fmaf(w, 1.3888888890e-3f, 8.3333333333e-3f);  // 1/720, 1/120
    t = fmaf(t, w, 4.1666666667e-2f);                       // 1/24
    t = fmaf(t, w, 1.6666666667e-1f);                       // 1/6
    t = fmaf(t, w, 0.5f);
    t = fmaf(t, w, 1.0f);
    return fmaf(t, w, 1.0f);
}

// Fragment packing (one b128 store per thread, 2560 threads = grid 10 x 256):
// brf[((i*8+et)*64 + l)*8 + j] = bf16(br[i][et*32+(l&31)][8*(l>>5)+j] * cA2_i)
// crf[((et*2+h)*64 + l)*8 + j] = b=l&31: b<16 ? cr[b][e] : (b==16 ? 1 : 0),
//                                e = et*32 + h*16 + 8*(l>>5) + j
__global__ void tt_prep(const float* __restrict__ ar,
                        const float* __restrict__ br,
                        const float* __restrict__ cr,
                        unsigned short* __restrict__ wsf)
{
    const int t = blockIdx.x * 256 + threadIdx.x;   // 0..2559
    float cA2[NI];
#pragma unroll
    for (int i = 0; i < NI; ++i) {
        float A = ar[0 * NI + i] + ar[1 * NI + i] + ar[2 * NI + i];
        cA2[i] = A * 0.17677669529663687f;          // NATURAL-log domain (no log2e)
    }
    if (t < BR_UNITS) {
        const int l = t & 63, et = (t >> 6) & 7, i = t >> 9;
        const float* src = br + (i * DD + et * 32 + (l & 31)) * R2 + 8 * (l >> 5);
        const float sc = cA2[i];
        ushort8 v;
#pragma unroll
        for (int j = 0; j < 8; ++j) v[j] = bf16bits(src[j] * sc);
        *(ushort8*)(wsf + t * 8) = v;
    } else {
        const int idx = t - BR_UNITS;               // 0..1023
        const int l = idx & 63, h = (idx >> 6) & 1, et = idx >> 7;
        const int b = l & 31;
        ushort8 v;
#pragma unroll
        for (int j = 0; j < 8; ++j) {
            const int e = et * 32 + h * 16 + 8 * (l >> 5) + j;
            float val = (b < 16) ? cr[b * DD + e] : (b == 16 ? 1.0f : 0.0f);
            v[j] = bf16bits(val);
        }
        *(ushort8*)(wsf + (BR_USH + idx * 8)) = v;
    }
}

__global__ __launch_bounds__(256, 4) void tt_attn_mfma(
    const float* __restrict__ x,
    const unsigned short* __restrict__ wsf,
    float* __restrict__ out)
{
    __shared__ unsigned short lds[WS_USH];          // 40960 B: 4 blocks/CU

    const int s     = blockIdx.x >> 1;
    const int dhalf = blockIdx.x & 1;
    const int tid   = threadIdx.x;
    const int lane  = tid & 63;
    const int wv    = tid >> 6;
    const int hi    = lane >> 5;
    const int d     = dhalf * 128 + wv * 32 + (lane & 31);

    // Stage all weight fragments to LDS: 10 chunks x 256 threads x 16 B = 40 KB.
#pragma unroll
    for (int c = 0; c < 10; ++c) {
        const char* g = (const char*)wsf + (size_t)(c * 256 + tid) * 16;
        char* lp = (char*)lds + (size_t)(c * 256 + wv * 64) * 16;
        __builtin_amdgcn_global_load_lds(
            (const __attribute__((address_space(1))) void*)g,
            (__attribute__((address_space(3))) void*)lp, 16, 0, 0);
    }

    // x fragment (issues while LDS staging is in flight):
    // lane holds x[q = 8*hi + j][s][d]  (B-operand of stage 1)
    const float* xp = x + s * DD + d + (hi ? 8 * SS * DD : 0);
    float xr[8];
#pragma unroll
    for (int t = 0; t < 8; ++t) xr[t] = xp[t * SS * DD];
    B8 xb;
#pragma unroll
    for (int t = 0; t < 4; ++t) xb.w[t] = packb(xr[2 * t], xr[2 * t + 1]);
    const bf16x8 xf = xb.v;

    __syncthreads();   // drains vmcnt (global_load_lds) per compiler semantics

    f32x16 acc0{}, acc1{}, acc2{};
    const f32x16 zf{};

    const unsigned short* brl = lds + lane * 8;
    const unsigned short* crl = lds + BR_USH + lane * 8;

#pragma unroll 2
    for (int et = 0; et < 8; ++et) {
        const bf16x8 crA0 = *(const bf16x8*)(crl + (et * 2 + 0) * 512);
        const bf16x8 crA1 = *(const bf16x8*)(crl + (et * 2 + 1) * 512);
#pragma unroll
        for (int i = 0; i < NI; ++i) {
            const bf16x8 brA = *(const bf16x8*)(brl + (i * 8 + et) * 512);
            f32x16 g = __builtin_amdgcn_mfma_f32_32x32x16_bf16(brA, xf, zf, 0, 0, 0);
            // P = exp(W) via 6-FMA polynomial (no trans-pipe usage)
            float p[16];
#pragma unroll
            for (int r = 0; r < 16; ++r) p[r] = exp_poly(g[r]);
            const unsigned w01 = packb(p[0],  p[1]);
            const unsigned w23 = packb(p[2],  p[3]);
            const unsigned w45 = packb(p[4],  p[5]);
            const unsigned w67 = packb(p[6],  p[7]);
            const unsigned w89 = packb(p[8],  p[9]);
            const unsigned wAB = packb(p[10], p[11]);
            const unsigned wCD = packb(p[12], p[13]);
            const unsigned wEF = packb(p[14], p[15]);
            // lane<->lane+32 half exchange: one swap fills two B-frag words
            const uint2v s0 = __builtin_amdgcn_permlane32_swap(w01, w45, false, false);
            const uint2v s1 = __builtin_amdgcn_permlane32_swap(w23, w67, false, false);
            const uint2v s2 = __builtin_amdgcn_permlane32_swap(w89, wCD, false, false);
            const uint2v s3 = __builtin_amdgcn_permlane32_swap(wAB, wEF, false, false);
            B8 P0; P0.w[0] = s0.x; P0.w[1] = s1.x; P0.w[2] = s0.y; P0.w[3] = s1.y;
            B8 P1; P1.w[0] = s2.x; P1.w[1] = s3.x; P1.w[2] = s2.y; P1.w[3] = s3.y;
            if (i == 0) {
                acc0 = __builtin_amdgcn_mfma_f32_32x32x16_bf16(crA0, P0.v, acc0, 0, 0, 0);
                acc0 = __builtin_amdgcn_mfma_f32_32x32x16_bf16(crA1, P1.v, acc0, 0, 0, 0);
            } else if (i == 1) {
                acc1 = __builtin_amdgcn_mfma_f32_32x32x16_bf16(crA0, P0.v, acc1, 0, 0, 0);
                acc1 = __builtin_amdgcn_mfma_f32_32x32x16_bf16(crA1, P1.v, acc1, 0, 0, 0);
            } else {
                acc2 = __builtin_amdgcn_mfma_f32_32x32x16_bf16(crA0, P0.v, acc2, 0, 0, 0);
                acc2 = __builtin_amdgcn_mfma_f32_32x32x16_bf16(crA1, P1.v, acc2, 0, 0, 0);
            }
        }
    }

    // l_i sits in C row 16 = reg 8 of hi=0 lanes; broadcast to hi=1 half
    float inv[NI];
#pragma unroll
    for (int i = 0; i < NI; ++i) {
        union { float f; unsigned u; } c;
        c.f = (i == 0) ? acc0[8] : (i == 1) ? acc1[8] : acc2[8];
        const uint2v r = __builtin_amdgcn_permlane32_swap(c.u, c.u, false, false);
        union { unsigned u; float f; } c2; c2.u = r.x;
        inv[i] = 1.0f / c2.f;
    }

#pragma unroll
    for (int r = 0; r < 8; ++r) {
        const int b = (r & 3) + 8 * (r >> 2) + 4 * hi;
        const float o = acc0[r] * inv[0] + acc1[r] * inv[1] + acc2[r] * inv[2];
        out[(b * SS + s) * DD + d] = o;
    }
}

extern "C" void kernel_launch(void* const* d_in, const int* in_sizes, int n_in,
                              void* d_out, int out_size, void* d_ws, size_t ws_size,
                              hipStream_t stream) {
    const float* x  = (const float*)d_in[0];
    const float* ar = (const float*)d_in[1];
    const float* br = (const float*)d_in[2];
    const float* cr = (const float*)d_in[3];
    float* out = (float*)d_out;

    unsigned short* wsf = (unsigned short*)d_ws;   // 40 KB: brf (24K) then crf (16K)

    hipLaunchKernelGGL(tt_prep, dim3(10), dim3(256), 0, stream, ar, br, cr, wsf);
    hipLaunchKernelGGL(tt_attn_mfma, dim3(SS * 2), dim3(256), 0, stream, x, wsf, out);
}

// Round 12
// 23.716 us; speedup vs baseline: 1.4911x; 1.4911x over previous
//
#include <hip/hip_runtime.h>
#include <hip/hip_bf16.h>
#include <math.h>

// TTMultiheadAttention via MFMA (round 11 = round 4 + v_perm_b32 pack):
//   per s:  G_i[e,d] = sum_q brs_i[e,q] * x[q,s,d]      (mfma 32x32x16 bf16)
//           P_i = exp2(G_i)   (brs pre-scaled by cA2_i*log2e/sqrt(32))
//           OUT_i[b,d] = sum_e CrT[b,e] * P_i[e,d]      (mfma, b row 16 = ones -> l_i)
//           out[b,s,d] = sum_i OUT_i[b,d] / l_i[d]
// Round-11 change (r10 calibration: compute is VALU-ISSUE-bound at 2cyc/instr;
// the multi-instr __float22bfloat162_rn RNE pack ~1000+ instr/wave is the
// largest elective block): pack P pairs with ONE v_perm_b32 (byte-select of
// the two floats' high halves = truncation-rounded bf16). The truncation bias
// cancels in the softmax ratio because the ones-row denominator uses the SAME
// truncated P. Everything else byte-identical to round 4 (best, 27.65us).

#define SS 512
#define DD 256
#define R2 16
#define NI 3

#define BR_UNITS (NI * 8 * 64)              // 1536 x 16B
#define CR_UNITS (16 * 64)                  // 1024 x 16B
#define ALL_UNITS (BR_UNITS + CR_UNITS)     // 2560 x 16B = 40 KB
#define BR_USH (BR_UNITS * 8)               // 12288 ushorts
#define WS_USH (ALL_UNITS * 8)              // 20480 ushorts

typedef __attribute__((ext_vector_type(8))) short bf16x8;
typedef __attribute__((ext_vector_type(8))) unsigned short ushort8;
typedef __attribute__((ext_vector_type(16))) float f32x16;
typedef __attribute__((ext_vector_type(2))) unsigned uint2v;

union B8 { unsigned w[4]; bf16x8 v; };

static __device__ __forceinline__ unsigned short bf16bits(float f) {
    union { __hip_bfloat16 h; unsigned short u; } c;
    c.h = __float2bfloat16(f);
    return c.u;
}
static __device__ __forceinline__ unsigned packb(float a, float b) {
    union { __hip_bfloat162 h; unsigned u; } c;
    c.h = __float22bfloat162_rn(make_float2(a, b));
    return c.u;
}
// ONE-instruction pack: dst = {b[31:16], a[31:16]} = {bf16_trunc(b), bf16_trunc(a)}
// v_perm_b32 byte-select: sel bytes 0..3 pick S1 bytes, 4..7 pick S0 bytes.
static __device__ __forceinline__ unsigned permpack(float a, float b) {
    union { float f; unsigned u; } ua, ub;
    ua.f = a; ub.f = b;
    return __builtin_amdgcn_perm(ub.u, ua.u, 0x07060302u);
}

// Fragment packing (one b128 store per thread, 2560 threads = grid 10 x 256):
// brf[((i*8+et)*64 + l)*8 + j] = bf16(br[i][et*32+(l&31)][8*(l>>5)+j] * cA2_i)
// crf[((et*2+h)*64 + l)*8 + j] = b=l&31: b<16 ? cr[b][e] : (b==16 ? 1 : 0),
//                                e = et*32 + h*16 + 8*(l>>5) + j
__global__ void tt_prep(const float* __restrict__ ar,
                        const float* __restrict__ br,
                        const float* __restrict__ cr,
                        unsigned short* __restrict__ wsf)
{
    const int t = blockIdx.x * 256 + threadIdx.x;   // 0..2559
    float cA2[NI];
#pragma unroll
    for (int i = 0; i < NI; ++i) {
        float A = ar[0 * NI + i] + ar[1 * NI + i] + ar[2 * NI + i];
        cA2[i] = A * (0.17677669529663687f * 1.4426950408889634f);
    }
    if (t < BR_UNITS) {
        const int l = t & 63, et = (t >> 6) & 7, i = t >> 9;
        const float* src = br + (i * DD + et * 32 + (l & 31)) * R2 + 8 * (l >> 5);
        const float sc = cA2[i];
        ushort8 v;
#pragma unroll
        for (int j = 0; j < 8; ++j) v[j] = bf16bits(src[j] * sc);
        *(ushort8*)(wsf + t * 8) = v;
    } else {
        const int idx = t - BR_UNITS;               // 0..1023
        const int l = idx & 63, h = (idx >> 6) & 1, et = idx >> 7;
        const int b = l & 31;
        ushort8 v;
#pragma unroll
        for (int j = 0; j < 8; ++j) {
            const int e = et * 32 + h * 16 + 8 * (l >> 5) + j;
            float val = (b < 16) ? cr[b * DD + e] : (b == 16 ? 1.0f : 0.0f);
            v[j] = bf16bits(val);
        }
        *(ushort8*)(wsf + (BR_USH + idx * 8)) = v;
    }
}

__global__ __launch_bounds__(256, 4) void tt_attn_mfma(
    const float* __restrict__ x,
    const unsigned short* __restrict__ wsf,
    float* __restrict__ out)
{
    __shared__ unsigned short lds[WS_USH];          // 40960 B: 4 blocks/CU

    const int s     = blockIdx.x >> 1;
    const int dhalf = blockIdx.x & 1;
    const int tid   = threadIdx.x;
    const int lane  = tid & 63;
    const int wv    = tid >> 6;
    const int hi    = lane >> 5;
    const int d     = dhalf * 128 + wv * 32 + (lane & 31);

    // Stage all weight fragments to LDS: 10 chunks x 256 threads x 16 B = 40 KB.
#pragma unroll
    for (int c = 0; c < 10; ++c) {
        const char* g = (const char*)wsf + (size_t)(c * 256 + tid) * 16;
        char* lp = (char*)lds + (size_t)(c * 256 + wv * 64) * 16;
        __builtin_amdgcn_global_load_lds(
            (const __attribute__((address_space(1))) void*)g,
            (__attribute__((address_space(3))) void*)lp, 16, 0, 0);
    }

    // x fragment (issues while LDS staging is in flight):
    // lane holds x[q = 8*hi + j][s][d]  (B-operand of stage 1)
    const float* xp = x + s * DD + d + (hi ? 8 * SS * DD : 0);
    float xr[8];
#pragma unroll
    for (int t = 0; t < 8; ++t) xr[t] = xp[t * SS * DD];
    B8 xb;
#pragma unroll
    for (int t = 0; t < 4; ++t) xb.w[t] = packb(xr[2 * t], xr[2 * t + 1]);  // RNE (once)
    const bf16x8 xf = xb.v;

    __syncthreads();   // drains vmcnt (global_load_lds) per compiler semantics

    f32x16 acc0{}, acc1{}, acc2{};
    const f32x16 zf{};

    const unsigned short* brl = lds + lane * 8;
    const unsigned short* crl = lds + BR_USH + lane * 8;

#pragma unroll 2
    for (int et = 0; et < 8; ++et) {
        const bf16x8 crA0 = *(const bf16x8*)(crl + (et * 2 + 0) * 512);
        const bf16x8 crA1 = *(const bf16x8*)(crl + (et * 2 + 1) * 512);
#pragma unroll
        for (int i = 0; i < NI; ++i) {
            const bf16x8 brA = *(const bf16x8*)(brl + (i * 8 + et) * 512);
            f32x16 g = __builtin_amdgcn_mfma_f32_32x32x16_bf16(brA, xf, zf, 0, 0, 0);
            float p[16];
#pragma unroll
            for (int r = 0; r < 16; ++r) p[r] = __builtin_amdgcn_exp2f(g[r]);
            // single-instruction truncation packs (bias cancels in softmax ratio)
            const unsigned w01 = permpack(p[0],  p[1]);
            const unsigned w23 = permpack(p[2],  p[3]);
            const unsigned w45 = permpack(p[4],  p[5]);
            const unsigned w67 = permpack(p[6],  p[7]);
            const unsigned w89 = permpack(p[8],  p[9]);
            const unsigned wAB = permpack(p[10], p[11]);
            const unsigned wCD = permpack(p[12], p[13]);
            const unsigned wEF = permpack(p[14], p[15]);
            // lane<->lane+32 half exchange: one swap fills two B-frag words
            const uint2v s0 = __builtin_amdgcn_permlane32_swap(w01, w45, false, false);
            const uint2v s1 = __builtin_amdgcn_permlane32_swap(w23, w67, false, false);
            const uint2v s2 = __builtin_amdgcn_permlane32_swap(w89, wCD, false, false);
            const uint2v s3 = __builtin_amdgcn_permlane32_swap(wAB, wEF, false, false);
            B8 P0; P0.w[0] = s0.x; P0.w[1] = s1.x; P0.w[2] = s0.y; P0.w[3] = s1.y;
            B8 P1; P1.w[0] = s2.x; P1.w[1] = s3.x; P1.w[2] = s2.y; P1.w[3] = s3.y;
            if (i == 0) {
                acc0 = __builtin_amdgcn_mfma_f32_32x32x16_bf16(crA0, P0.v, acc0, 0, 0, 0);
                acc0 = __builtin_amdgcn_mfma_f32_32x32x16_bf16(crA1, P1.v, acc0, 0, 0, 0);
            } else if (i == 1) {
                acc1 = __builtin_amdgcn_mfma_f32_32x32x16_bf16(crA0, P0.v, acc1, 0, 0, 0);
                acc1 = __builtin_amdgcn_mfma_f32_32x32x16_bf16(crA1, P1.v, acc1, 0, 0, 0);
            } else {
                acc2 = __builtin_amdgcn_mfma_f32_32x32x16_bf16(crA0, P0.v, acc2, 0, 0, 0);
                acc2 = __builtin_amdgcn_mfma_f32_32x32x16_bf16(crA1, P1.v, acc2, 0, 0, 0);
            }
        }
    }

    // l_i sits in C row 16 = reg 8 of hi=0 lanes; broadcast to hi=1 half
    float inv[NI];
#pragma unroll
    for (int i = 0; i < NI; ++i) {
        union { float f; unsigned u; } c;
        c.f = (i == 0) ? acc0[8] : (i == 1) ? acc1[8] : acc2[8];
        const uint2v r = __builtin_amdgcn_permlane32_swap(c.u, c.u, false, false);
        union { unsigned u; float f; } c2; c2.u = r.x;
        inv[i] = 1.0f / c2.f;
    }

#pragma unroll
    for (int r = 0; r < 8; ++r) {
        const int b = (r & 3) + 8 * (r >> 2) + 4 * hi;
        const float o = acc0[r] * inv[0] + acc1[r] * inv[1] + acc2[r] * inv[2];
        out[(b * SS + s) * DD + d] = o;
    }
}

extern "C" void kernel_launch(void* const* d_in, const int* in_sizes, int n_in,
                              void* d_out, int out_size, void* d_ws, size_t ws_size,
                              hipStream_t stream) {
    const float* x  = (const float*)d_in[0];
    const float* ar = (const float*)d_in[1];
    const float* br = (const float*)d_in[2];
    const float* cr = (const float*)d_in[3];
    float* out = (float*)d_out;

    unsigned short* wsf = (unsigned short*)d_ws;   // 40 KB: brf (24K) then crf (16K)

    hipLaunchKernelGGL(tt_prep, dim3(10), dim3(256), 0, stream, ar, br, cr, wsf);
    hipLaunchKernelGGL(tt_attn_mfma, dim3(SS * 2), dim3(256), 0, stream, x, wsf, out);
}

// Round 13
// 22.657 us; speedup vs baseline: 1.5608x; 1.0467x over previous
//
#include <hip/hip_runtime.h>
#include <hip/hip_bf16.h>
#include <math.h>

// TTMultiheadAttention via MFMA (round 12 = round 11 + permuted-CrT, no permlane):
//   per s:  G_i[e,d] = sum_q brs_i[e,q] * x[q,s,d]      (mfma 32x32x16 bf16)
//           P_i = exp2(G_i)   (brs pre-scaled by cA2_i*log2e/sqrt(32))
//           OUT_i[b,d] = sum_e CrT[b,e] * P_i[e,d]      (mfma, b row 16 = ones -> l_i)
//           out[b,s,d] = sum_i OUT_i[b,d] / l_i[d]
// Round-12 change: MFMA's k-contraction is invariant under a common k-slot
// permutation of A and B. Stage-1's C-layout leaves P at k-slot (j,hi) ->
// logical e = (j&3)+8(j>>2)+4hi; apply the SAME sigma to the CrT fragment in
// tt_prep (index math, free). The permpack words then feed stage-2's B operand
// DIRECTLY: the 4 permlane32_swap + fragment reassembly per (et,i) vanish and
// the pack->swap->MFMA chain loses a stage. Everything else = round 11.

#define SS 512
#define DD 256
#define R2 16
#define NI 3

#define BR_UNITS (NI * 8 * 64)              // 1536 x 16B
#define CR_UNITS (16 * 64)                  // 1024 x 16B
#define ALL_UNITS (BR_UNITS + CR_UNITS)     // 2560 x 16B = 40 KB
#define BR_USH (BR_UNITS * 8)               // 12288 ushorts
#define WS_USH (ALL_UNITS * 8)              // 20480 ushorts

typedef __attribute__((ext_vector_type(8))) short bf16x8;
typedef __attribute__((ext_vector_type(8))) unsigned short ushort8;
typedef __attribute__((ext_vector_type(16))) float f32x16;
typedef __attribute__((ext_vector_type(2))) unsigned uint2v;

union B8 { unsigned w[4]; bf16x8 v; };

static __device__ __forceinline__ unsigned short bf16bits(float f) {
    union { __hip_bfloat16 h; unsigned short u; } c;
    c.h = __float2bfloat16(f);
    return c.u;
}
static __device__ __forceinline__ unsigned packb(float a, float b) {
    union { __hip_bfloat162 h; unsigned u; } c;
    c.h = __float22bfloat162_rn(make_float2(a, b));
    return c.u;
}
// ONE-instruction pack: dst = {b[31:16], a[31:16]} = {bf16_trunc(b), bf16_trunc(a)}
static __device__ __forceinline__ unsigned permpack(float a, float b) {
    union { float f; unsigned u; } ua, ub;
    ua.f = a; ub.f = b;
    return __builtin_amdgcn_perm(ub.u, ua.u, 0x07060302u);
}

// Fragment packing (one b128 store per thread, 2560 threads = grid 10 x 256):
// brf[((i*8+et)*64 + l)*8 + j] = bf16(br[i][et*32+(l&31)][8*(l>>5)+j] * cA2_i)
// crf: k-slot-permuted CrT (+ ones row at b==16):
//   crf[((et*2+h)*64 + l)*8 + j] = b=l&31: b<16 ? cr[b][e] : (b==16 ? 1 : 0),
//   e = et*32 + h*16 + (j&3) + 8*(j>>2) + 4*(l>>5)     <-- sigma(k-slot)
__global__ void tt_prep(const float* __restrict__ ar,
                        const float* __restrict__ br,
                        const float* __restrict__ cr,
                        unsigned short* __restrict__ wsf)
{
    const int t = blockIdx.x * 256 + threadIdx.x;   // 0..2559
    float cA2[NI];
#pragma unroll
    for (int i = 0; i < NI; ++i) {
        float A = ar[0 * NI + i] + ar[1 * NI + i] + ar[2 * NI + i];
        cA2[i] = A * (0.17677669529663687f * 1.4426950408889634f);
    }
    if (t < BR_UNITS) {
        const int l = t & 63, et = (t >> 6) & 7, i = t >> 9;
        const float* src = br + (i * DD + et * 32 + (l & 31)) * R2 + 8 * (l >> 5);
        const float sc = cA2[i];
        ushort8 v;
#pragma unroll
        for (int j = 0; j < 8; ++j) v[j] = bf16bits(src[j] * sc);
        *(ushort8*)(wsf + t * 8) = v;
    } else {
        const int idx = t - BR_UNITS;               // 0..1023
        const int l = idx & 63, h = (idx >> 6) & 1, et = idx >> 7;
        const int b = l & 31;
        ushort8 v;
#pragma unroll
        for (int j = 0; j < 8; ++j) {
            // sigma-permuted k-slot -> logical e (matches P's C-layout residence)
            const int e = et * 32 + h * 16 + (j & 3) + 8 * (j >> 2) + 4 * (l >> 5);
            float val = (b < 16) ? cr[b * DD + e] : (b == 16 ? 1.0f : 0.0f);
            v[j] = bf16bits(val);
        }
        *(ushort8*)(wsf + (BR_USH + idx * 8)) = v;
    }
}

__global__ __launch_bounds__(256, 4) void tt_attn_mfma(
    const float* __restrict__ x,
    const unsigned short* __restrict__ wsf,
    float* __restrict__ out)
{
    __shared__ unsigned short lds[WS_USH];          // 40960 B: 4 blocks/CU

    const int s     = blockIdx.x >> 1;
    const int dhalf = blockIdx.x & 1;
    const int tid   = threadIdx.x;
    const int lane  = tid & 63;
    const int wv    = tid >> 6;
    const int hi    = lane >> 5;
    const int d     = dhalf * 128 + wv * 32 + (lane & 31);

    // Stage all weight fragments to LDS: 10 chunks x 256 threads x 16 B = 40 KB.
#pragma unroll
    for (int c = 0; c < 10; ++c) {
        const char* g = (const char*)wsf + (size_t)(c * 256 + tid) * 16;
        char* lp = (char*)lds + (size_t)(c * 256 + wv * 64) * 16;
        __builtin_amdgcn_global_load_lds(
            (const __attribute__((address_space(1))) void*)g,
            (__attribute__((address_space(3))) void*)lp, 16, 0, 0);
    }

    // x fragment (issues while LDS staging is in flight):
    // lane holds x[q = 8*hi + j][s][d]  (B-operand of stage 1)
    const float* xp = x + s * DD + d + (hi ? 8 * SS * DD : 0);
    float xr[8];
#pragma unroll
    for (int t = 0; t < 8; ++t) xr[t] = xp[t * SS * DD];
    B8 xb;
#pragma unroll
    for (int t = 0; t < 4; ++t) xb.w[t] = packb(xr[2 * t], xr[2 * t + 1]);  // RNE (once)
    const bf16x8 xf = xb.v;

    __syncthreads();   // drains vmcnt (global_load_lds) per compiler semantics

    f32x16 acc0{}, acc1{}, acc2{};
    const f32x16 zf{};

    const unsigned short* brl = lds + lane * 8;
    const unsigned short* crl = lds + BR_USH + lane * 8;

#pragma unroll 2
    for (int et = 0; et < 8; ++et) {
        const bf16x8 crA0 = *(const bf16x8*)(crl + (et * 2 + 0) * 512);
        const bf16x8 crA1 = *(const bf16x8*)(crl + (et * 2 + 1) * 512);
#pragma unroll
        for (int i = 0; i < NI; ++i) {
            const bf16x8 brA = *(const bf16x8*)(brl + (i * 8 + et) * 512);
            f32x16 g = __builtin_amdgcn_mfma_f32_32x32x16_bf16(brA, xf, zf, 0, 0, 0);
            float p[16];
#pragma unroll
            for (int r = 0; r < 16; ++r) p[r] = __builtin_amdgcn_exp2f(g[r]);
            // packs feed stage-2 B operand DIRECTLY (k-slots sigma-permuted on A side)
            B8 P0, P1;
            P0.w[0] = permpack(p[0],  p[1]);
            P0.w[1] = permpack(p[2],  p[3]);
            P0.w[2] = permpack(p[4],  p[5]);
            P0.w[3] = permpack(p[6],  p[7]);
            P1.w[0] = permpack(p[8],  p[9]);
            P1.w[1] = permpack(p[10], p[11]);
            P1.w[2] = permpack(p[12], p[13]);
            P1.w[3] = permpack(p[14], p[15]);
            if (i == 0) {
                acc0 = __builtin_amdgcn_mfma_f32_32x32x16_bf16(crA0, P0.v, acc0, 0, 0, 0);
                acc0 = __builtin_amdgcn_mfma_f32_32x32x16_bf16(crA1, P1.v, acc0, 0, 0, 0);
            } else if (i == 1) {
                acc1 = __builtin_amdgcn_mfma_f32_32x32x16_bf16(crA0, P0.v, acc1, 0, 0, 0);
                acc1 = __builtin_amdgcn_mfma_f32_32x32x16_bf16(crA1, P1.v, acc1, 0, 0, 0);
            } else {
                acc2 = __builtin_amdgcn_mfma_f32_32x32x16_bf16(crA0, P0.v, acc2, 0, 0, 0);
                acc2 = __builtin_amdgcn_mfma_f32_32x32x16_bf16(crA1, P1.v, acc2, 0, 0, 0);
            }
        }
    }

    // l_i sits in C row 16 = reg 8 of hi=0 lanes; broadcast to hi=1 half
    float inv[NI];
#pragma unroll
    for (int i = 0; i < NI; ++i) {
        union { float f; unsigned u; } c;
        c.f = (i == 0) ? acc0[8] : (i == 1) ? acc1[8] : acc2[8];
        const uint2v r = __builtin_amdgcn_permlane32_swap(c.u, c.u, false, false);
        union { unsigned u; float f; } c2; c2.u = r.x;
        inv[i] = 1.0f / c2.f;
    }

#pragma unroll
    for (int r = 0; r < 8; ++r) {
        const int b = (r & 3) + 8 * (r >> 2) + 4 * hi;
        const float o = acc0[r] * inv[0] + acc1[r] * inv[1] + acc2[r] * inv[2];
        out[(b * SS + s) * DD + d] = o;
    }
}

extern "C" void kernel_launch(void* const* d_in, const int* in_sizes, int n_in,
                              void* d_out, int out_size, void* d_ws, size_t ws_size,
                              hipStream_t stream) {
    const float* x  = (const float*)d_in[0];
    const float* ar = (const float*)d_in[1];
    const float* br = (const float*)d_in[2];
    const float* cr = (const float*)d_in[3];
    float* out = (float*)d_out;

    unsigned short* wsf = (unsigned short*)d_ws;   // 40 KB: brf (24K) then crf (16K)

    hipLaunchKernelGGL(tt_prep, dim3(10), dim3(256), 0, stream, ar, br, cr, wsf);
    hipLaunchKernelGGL(tt_attn_mfma, dim3(SS * 2), dim3(256), 0, stream, x, wsf, out);
}